// Round 1
// 238.590 us; speedup vs baseline: 1.0028x; 1.0028x over previous
//
#include <hip/hip_runtime.h>
#include <math.h>

// Problem constants (B=4, T=4096, D=2048, K=4)
#define D_DIM 2048
#define T_DIM 4096
#define TT    16               // output rows per block
#define NT    (D_DIM / 4)      // 512 threads: block spans full D, float4/thread
#define NW    (NT / 64)        // 8 waves

typedef float vfloat4 __attribute__((ext_vector_type(4)));  // native vec for nontemporal builtin

// intra-wave sum of squares of a float4, reduced across 64 lanes
__device__ __forceinline__ float row_partial(float4 v) {
    float p = v.x * v.x + v.y * v.y + v.z * v.z + v.w * v.w;
#pragma unroll
    for (int off = 32; off > 0; off >>= 1) p += __shfl_down(p, off, 64);
    return p;
}

// sum 8 wave-partials (two broadcast float4 LDS reads) -> inverse RMS
__device__ __forceinline__ float inv_from(const float* sp) {
    float4 a = *(const float4*)sp;
    float4 b = *(const float4*)(sp + 4);
    float s = a.x + a.y + a.z + a.w + b.x + b.y + b.z + b.w;
    return rsqrtf(s * (1.0f / D_DIM) + 1e-5f);
}

__device__ __forceinline__ float silu(float v) {
    return v * __builtin_amdgcn_rcpf(1.f + __expf(-v));
}

__device__ __forceinline__ void nt_store4(float* p, float a, float b, float c, float d) {
    vfloat4 v = { a, b, c, d };
    __builtin_nontemporal_store(v, (vfloat4*)p);
}

// Restructured fused kernel: issue ALL 19 row loads up front (max MLP),
// compute all 19 wave-partials (independent shfl chains), take ONE barrier,
// then do the full normalize -> causal depthwise conv K=4 -> SiLU sweep
// with zero further synchronization. Removes the 8-barrier serialized
// pipeline that capped load issue rate at ~4 B/cyc/CU.
__global__ __launch_bounds__(NT, 4) void fused_kernel(
    const float* __restrict__ x,
    const float* __restrict__ g,
    const float* __restrict__ w,
    float* __restrict__ out)
{
    const int b    = blockIdx.y;
    const int t0   = blockIdx.x * TT;
    const int tid  = threadIdx.x;
    const int d0   = tid * 4;
    const int lane = tid & 63;
    const int wid  = tid >> 6;

    __shared__ __align__(16) float part[TT + 3][NW];   // 19 rows x 8 waves = 608 B

    const float* xb = x   + (size_t)b * T_DIM * D_DIM + d0;
    float*       ob = out + (size_t)b * T_DIM * D_DIM + d0;

    // ---- issue ALL loads up front: 3 halo rows + 16 main rows ----
    float4 hv[3];
#pragma unroll
    for (int r = 0; r < 3; ++r) {
        const int t = t0 - 3 + r;
        hv[r] = (t >= 0) ? *(const float4*)(xb + (size_t)t * D_DIM)
                         : make_float4(0.f, 0.f, 0.f, 0.f);
    }
    float4 xv[TT];
#pragma unroll
    for (int i = 0; i < TT; ++i)
        xv[i] = *(const float4*)(xb + (size_t)(t0 + i) * D_DIM);

    const float4 gv = *(const float4*)(g + d0);
    float wgt[4][4];
#pragma unroll
    for (int j = 0; j < 4; ++j) {
        float4 wv = *(const float4*)(w + (size_t)(d0 + j) * 4);
        wgt[j][0] = wv.x; wgt[j][1] = wv.y; wgt[j][2] = wv.z; wgt[j][3] = wv.w;
    }

    // ---- all 19 partial sums, then a single barrier ----
#pragma unroll
    for (int r = 0; r < 3; ++r) {
        float p = row_partial(hv[r]);
        if (lane == 0) part[r][wid] = p;
    }
#pragma unroll
    for (int i = 0; i < TT; ++i) {
        float p = row_partial(xv[i]);
        if (lane == 0) part[3 + i][wid] = p;
    }
    __syncthreads();

    // ---- normalize halo rows into the sliding window ----
    float win[3][4];
#pragma unroll
    for (int r = 0; r < 3; ++r) {
        const float inv = inv_from(part[r]);
        win[r][0] = hv[r].x * inv * gv.x;
        win[r][1] = hv[r].y * inv * gv.y;
        win[r][2] = hv[r].z * inv * gv.z;
        win[r][3] = hv[r].w * inv * gv.w;
    }

    // ---- normalize + conv + SiLU + store, fully unrolled, no barriers ----
#pragma unroll
    for (int i = 0; i < TT; ++i) {
        const float inv = inv_from(part[3 + i]);
        const float y0[4] = { xv[i].x * inv * gv.x, xv[i].y * inv * gv.y,
                              xv[i].z * inv * gv.z, xv[i].w * inv * gv.w };
        float o0[4];
#pragma unroll
        for (int j = 0; j < 4; ++j) {
            const float v = wgt[j][0] * win[0][j] + wgt[j][1] * win[1][j] +
                            wgt[j][2] * win[2][j] + wgt[j][3] * y0[j];
            o0[j] = silu(v);
        }
        nt_store4(ob + (size_t)(t0 + i) * D_DIM, o0[0], o0[1], o0[2], o0[3]);

        // slide window by one row
#pragma unroll
        for (int j = 0; j < 4; ++j) {
            win[0][j] = win[1][j];
            win[1][j] = win[2][j];
            win[2][j] = y0[j];
        }
    }
}

extern "C" void kernel_launch(void* const* d_in, const int* in_sizes, int n_in,
                              void* d_out, int out_size, void* d_ws, size_t ws_size,
                              hipStream_t stream) {
    const float* x = (const float*)d_in[0];
    const float* g = (const float*)d_in[1];   // norm_weight [D]
    const float* w = (const float*)d_in[2];   // conv_weight [D,1,K]
    float* out = (float*)d_out;

    const int total = in_sizes[0];            // B*T*D
    const int rows  = total / D_DIM;          // B*T
    const int B     = rows / T_DIM;

    dim3 grid(T_DIM / TT, B);
    fused_kernel<<<grid, NT, 0, stream>>>(x, g, w, out);
}

// Round 2
// 237.952 us; speedup vs baseline: 1.0055x; 1.0027x over previous
//
#include <hip/hip_runtime.h>
#include <math.h>

// Problem constants (B=4, T=4096, D=2048, K=4)
#define D_DIM 2048
#define T_DIM 4096
#define TT    16               // output rows per block
#define NT    (D_DIM / 4)      // 512 threads: block spans full D, float4/thread
#define NW    (NT / 64)        // 8 waves

typedef float vfloat4 __attribute__((ext_vector_type(4)));  // native vec for nontemporal builtin

// intra-wave sum of squares of a float4, reduced across 64 lanes
__device__ __forceinline__ float row_partial(float4 v) {
    float p = v.x * v.x + v.y * v.y + v.z * v.z + v.w * v.w;
#pragma unroll
    for (int off = 32; off > 0; off >>= 1) p += __shfl_down(p, off, 64);
    return p;
}

// sum 8 wave-partials (two broadcast float4 LDS reads) -> inverse RMS
__device__ __forceinline__ float inv_from(const float* sp) {
    float4 a = *(const float4*)sp;
    float4 b = *(const float4*)(sp + 4);
    float s = a.x + a.y + a.z + a.w + b.x + b.y + b.z + b.w;
    return rsqrtf(s * (1.0f / D_DIM) + 1e-5f);
}

__device__ __forceinline__ float silu(float v) {
    return v * __builtin_amdgcn_rcpf(1.f + __expf(-v));
}

__device__ __forceinline__ void nt_store4(float* p, float a, float b, float c, float d) {
    vfloat4 v = { a, b, c, d };
    __builtin_nontemporal_store(v, (vfloat4*)p);
}

// R2: same single-barrier structure as R1, but __launch_bounds__(NT, 2)
// (<=256 VGPR) so the register allocator can afford to keep all 19 row
// float4s LIVE across the barrier instead of remat-reloading them.
// R1's VGPR_Count=64 proved the "all loads in flight" mechanism never
// engaged under the 128-VGPR cap. Target: ~130 VGPRs, 19 loads in
// flight per thread (304 B), ~155 KB outstanding per CU per block.
__global__ __launch_bounds__(NT, 2) void fused_kernel(
    const float* __restrict__ x,
    const float* __restrict__ g,
    const float* __restrict__ w,
    float* __restrict__ out)
{
    const int b    = blockIdx.y;
    const int t0   = blockIdx.x * TT;
    const int tid  = threadIdx.x;
    const int d0   = tid * 4;
    const int lane = tid & 63;
    const int wid  = tid >> 6;

    __shared__ __align__(16) float part[TT + 3][NW];   // 19 rows x 8 waves

    const float* xb = x   + (size_t)b * T_DIM * D_DIM + d0;
    float*       ob = out + (size_t)b * T_DIM * D_DIM + d0;

    // ---- issue ALL row loads up front: 3 halo rows + 16 main rows ----
    float4 hv[3];
#pragma unroll
    for (int r = 0; r < 3; ++r) {
        const int t = t0 - 3 + r;
        hv[r] = (t >= 0) ? *(const float4*)(xb + (size_t)t * D_DIM)
                         : make_float4(0.f, 0.f, 0.f, 0.f);
    }
    float4 xv[TT];
#pragma unroll
    for (int i = 0; i < TT; ++i)
        xv[i] = *(const float4*)(xb + (size_t)(t0 + i) * D_DIM);

    // small L2-resident parameter loads issued after the bulk row loads
    const float4 gv = *(const float4*)(g + d0);
    float wgt[4][4];
#pragma unroll
    for (int j = 0; j < 4; ++j) {
        float4 wv = *(const float4*)(w + (size_t)(d0 + j) * 4);
        wgt[j][0] = wv.x; wgt[j][1] = wv.y; wgt[j][2] = wv.z; wgt[j][3] = wv.w;
    }

    // ---- all 19 partial sums (independent shfl chains), ONE barrier ----
#pragma unroll
    for (int r = 0; r < 3; ++r) {
        float p = row_partial(hv[r]);
        if (lane == 0) part[r][wid] = p;
    }
#pragma unroll
    for (int i = 0; i < TT; ++i) {
        float p = row_partial(xv[i]);
        if (lane == 0) part[3 + i][wid] = p;
    }
    __syncthreads();

    // ---- normalize halo rows into the sliding window ----
    float win[3][4];
#pragma unroll
    for (int r = 0; r < 3; ++r) {
        const float inv = inv_from(part[r]);
        win[r][0] = hv[r].x * inv * gv.x;
        win[r][1] = hv[r].y * inv * gv.y;
        win[r][2] = hv[r].z * inv * gv.z;
        win[r][3] = hv[r].w * inv * gv.w;
    }

    // ---- normalize + conv + SiLU + store, fully unrolled, no barriers ----
#pragma unroll
    for (int i = 0; i < TT; ++i) {
        const float inv = inv_from(part[3 + i]);
        const float y0[4] = { xv[i].x * inv * gv.x, xv[i].y * inv * gv.y,
                              xv[i].z * inv * gv.z, xv[i].w * inv * gv.w };
        float o0[4];
#pragma unroll
        for (int j = 0; j < 4; ++j) {
            const float v = wgt[j][0] * win[0][j] + wgt[j][1] * win[1][j] +
                            wgt[j][2] * win[2][j] + wgt[j][3] * y0[j];
            o0[j] = silu(v);
        }
        nt_store4(ob + (size_t)(t0 + i) * D_DIM, o0[0], o0[1], o0[2], o0[3]);

        // slide window by one row
#pragma unroll
        for (int j = 0; j < 4; ++j) {
            win[0][j] = win[1][j];
            win[1][j] = win[2][j];
            win[2][j] = y0[j];
        }
    }
}

extern "C" void kernel_launch(void* const* d_in, const int* in_sizes, int n_in,
                              void* d_out, int out_size, void* d_ws, size_t ws_size,
                              hipStream_t stream) {
    const float* x = (const float*)d_in[0];
    const float* g = (const float*)d_in[1];   // norm_weight [D]
    const float* w = (const float*)d_in[2];   // conv_weight [D,1,K]
    float* out = (float*)d_out;

    const int total = in_sizes[0];            // B*T*D
    const int rows  = total / D_DIM;          // B*T
    const int B     = rows / T_DIM;

    dim3 grid(T_DIM / TT, B);
    fused_kernel<<<grid, NT, 0, stream>>>(x, g, w, out);
}

// Round 4
// 233.405 us; speedup vs baseline: 1.0251x; 1.0195x over previous
//
#include <hip/hip_runtime.h>
#include <math.h>

// Problem constants (B=4, T=4096, D=2048, K=4)
#define D_DIM 2048
#define T_DIM 4096
#define TT    8                // output rows per block (16->8: keeps forced-live rows under 128 VGPR)
#define NT    (D_DIM / 4)      // 512 threads: block spans full D, float4/thread
#define NW    (NT / 64)        // 8 waves
#define NROW  (TT + 3)         // halo (3) + main rows

typedef float vfloat4 __attribute__((ext_vector_type(4)));  // native vec for nontemporal builtin

__device__ __forceinline__ float sumsq4(float4 v) {
    return v.x * v.x + v.y * v.y + v.z * v.z + v.w * v.w;
}

// sum 8 wave-partials (two broadcast float4 LDS reads) -> inverse RMS
__device__ __forceinline__ float inv_from(const float* sp) {
    float4 a = *(const float4*)sp;
    float4 b = *(const float4*)(sp + 4);
    float s = a.x + a.y + a.z + a.w + b.x + b.y + b.z + b.w;
    return rsqrtf(s * (1.0f / D_DIM) + 1e-5f);
}

__device__ __forceinline__ float silu(float v) {
    return v * __builtin_amdgcn_rcpf(1.f + __expf(-v));
}

__device__ __forceinline__ void nt_store4(float* p, float a, float b, float c, float d) {
    vfloat4 v = { a, b, c, d };
    __builtin_nontemporal_store(v, (vfloat4*)p);
}

// R4 == R3 resubmitted (R3 failed on infra, not on the kernel).
// R1/R2's "all loads up front" plan failed because the scheduler
// (VGPR_Count stayed 64) sank each load next to its consumer, exposing a
// ~600cy per-row critical path (vmcnt wait + 6-dep shfl chain + LDS).
// This version FORCES the structure:
//   1. sched_barrier(0) after the load section - no instruction may cross,
//      so all 11 row loads issue before any consumer (true MLP).
//   2. level-outer/row-inner shuffle reduction - 11 independent DS ops
//      between dependent pairs, hiding the chain latency with ILP.
//   3. TT=8 so the forced-live state (~90 VGPR) stays under the 128-VGPR
//      occupancy line: 4 waves/SIMD, 2 blocks/CU resident.
__global__ __launch_bounds__(NT, 4) void fused_kernel(
    const float* __restrict__ x,
    const float* __restrict__ g,
    const float* __restrict__ w,
    float* __restrict__ out)
{
    const int b    = blockIdx.y;
    const int t0   = blockIdx.x * TT;
    const int tid  = threadIdx.x;
    const int d0   = tid * 4;
    const int lane = tid & 63;
    const int wid  = tid >> 6;

    __shared__ __align__(16) float part[NROW][NW];   // 11 rows x 8 waves

    const float* xb = x   + (size_t)b * T_DIM * D_DIM + d0;
    float*       ob = out + (size_t)b * T_DIM * D_DIM + d0;

    // ---- issue ALL row loads: rows t0-3 .. t0+TT-1 ----
    float4 rv[NROW];
#pragma unroll
    for (int r = 0; r < 3; ++r) {
        const int t = t0 - 3 + r;
        rv[r] = (t >= 0) ? *(const float4*)(xb + (size_t)t * D_DIM)
                         : make_float4(0.f, 0.f, 0.f, 0.f);
    }
#pragma unroll
    for (int i = 0; i < TT; ++i)
        rv[3 + i] = *(const float4*)(xb + (size_t)(t0 + i) * D_DIM);

    // small L2/L3-resident parameter loads
    const float4 gv = *(const float4*)(g + d0);
    float wgt[4][4];
#pragma unroll
    for (int j = 0; j < 4; ++j) {
        float4 wv = *(const float4*)(w + (size_t)(d0 + j) * 4);
        wgt[j][0] = wv.x; wgt[j][1] = wv.y; wgt[j][2] = wv.z; wgt[j][3] = wv.w;
    }

    // hard fence: nothing below may be hoisted above, nothing above may sink
    // below -> all loads are issued back-to-back, rows stay live in VGPRs.
    __builtin_amdgcn_sched_barrier(0);

    // ---- per-lane sums of squares (consumes loads in issue order) ----
    float p[NROW];
#pragma unroll
    for (int r = 0; r < NROW; ++r) p[r] = sumsq4(rv[r]);

    // ---- wave reduction, LEVEL-outer / ROW-inner: 11-wide ILP per level ----
#pragma unroll
    for (int off = 32; off > 0; off >>= 1) {
#pragma unroll
        for (int r = 0; r < NROW; ++r)
            p[r] += __shfl_down(p[r], off, 64);
    }
    if (lane == 0) {
#pragma unroll
        for (int r = 0; r < NROW; ++r) part[r][wid] = p[r];
    }
    __syncthreads();

    // ---- normalize halo rows into the sliding window ----
    float win[3][4];
#pragma unroll
    for (int r = 0; r < 3; ++r) {
        const float inv = inv_from(part[r]);
        win[r][0] = rv[r].x * inv * gv.x;
        win[r][1] = rv[r].y * inv * gv.y;
        win[r][2] = rv[r].z * inv * gv.z;
        win[r][3] = rv[r].w * inv * gv.w;
    }

    // ---- normalize + conv + SiLU + store, fully unrolled, no barriers ----
#pragma unroll
    for (int i = 0; i < TT; ++i) {
        const float inv = inv_from(part[3 + i]);
        const float4 xv = rv[3 + i];
        const float y0[4] = { xv.x * inv * gv.x, xv.y * inv * gv.y,
                              xv.z * inv * gv.z, xv.w * inv * gv.w };
        float o0[4];
#pragma unroll
        for (int j = 0; j < 4; ++j) {
            const float v = wgt[j][0] * win[0][j] + wgt[j][1] * win[1][j] +
                            wgt[j][2] * win[2][j] + wgt[j][3] * y0[j];
            o0[j] = silu(v);
        }
        nt_store4(ob + (size_t)(t0 + i) * D_DIM, o0[0], o0[1], o0[2], o0[3]);

        // slide window by one row
#pragma unroll
        for (int j = 0; j < 4; ++j) {
            win[0][j] = win[1][j];
            win[1][j] = win[2][j];
            win[2][j] = y0[j];
        }
    }
}

extern "C" void kernel_launch(void* const* d_in, const int* in_sizes, int n_in,
                              void* d_out, int out_size, void* d_ws, size_t ws_size,
                              hipStream_t stream) {
    const float* x = (const float*)d_in[0];
    const float* g = (const float*)d_in[1];   // norm_weight [D]
    const float* w = (const float*)d_in[2];   // conv_weight [D,1,K]
    float* out = (float*)d_out;

    const int total = in_sizes[0];            // B*T*D
    const int rows  = total / D_DIM;          // B*T
    const int B     = rows / T_DIM;

    dim3 grid(T_DIM / TT, B);
    fused_kernel<<<grid, NT, 0, stream>>>(x, g, w, out);
}

// Round 5
// 231.873 us; speedup vs baseline: 1.0318x; 1.0066x over previous
//
#include <hip/hip_runtime.h>
#include <math.h>

// Problem constants (B=4, T=4096, D=2048, K=4)
#define D_DIM 2048
#define T_DIM 4096
#define TT    4                // output rows per block
#define NT    512              // threads: block spans full D, float4/thread
#define NW    8                // waves per block
#define NROW  (TT + 3)         // 7 rows staged (3 halo + 4 main)
#define ROW_F D_DIM            // floats per row
#define AS1 __attribute__((address_space(1)))
#define AS3 __attribute__((address_space(3)))

typedef float vfloat4 __attribute__((ext_vector_type(4)));

__device__ __forceinline__ float silu(float v) {
    return v * __builtin_amdgcn_rcpf(1.f + __expf(-v));
}

__device__ __forceinline__ void nt_store4(float* p, float a, float b, float c, float d) {
    vfloat4 v = { a, b, c, d };
    __builtin_nontemporal_store(v, (vfloat4*)p);
}

// R5: R1-R4 proved the compiler will never keep VGPR-destined row loads in
// flight (VGPR_Count stayed 48-64 through launch_bounds relaxation AND
// sched_barrier(0)); all register-resident schedules plateau at 2.5 TB/s.
// This version stages rows via __builtin_amdgcn_global_load_lds: DMA with
// NO destination registers -> nothing for the scheduler to sink, all 7 row
// loads issue as a guaranteed burst (56 KB outstanding per block).
//   - wave w reduces row w wholly from LDS: one shfl chain per wave, no
//     cross-wave reduction tree, inv[] published directly.
//   - 56 KB LDS/block -> 2 blocks/CU: block A computes while block B DMAs.
//   - TT=4 doubles the grid (4096 blocks) for TLP.
__global__ __launch_bounds__(NT, 4) void fused_kernel(
    const float* __restrict__ x,
    const float* __restrict__ g,
    const float* __restrict__ w,
    float* __restrict__ out)
{
    const int b    = blockIdx.y;
    const int t0   = blockIdx.x * TT;
    const int tid  = threadIdx.x;
    const int d0   = tid * 4;
    const int lane = tid & 63;
    const int wid  = tid >> 6;

    __shared__ __align__(16) float rows[NROW * ROW_F];  // 57344 B
    __shared__ __align__(16) float inv_s[NROW];

    const float* xb = x + (size_t)b * T_DIM * D_DIM;

    // ---- stage all 7 rows into LDS: fire-and-forget 16B/lane DMA ----
    // lane i of the block covers bytes [tid*16, tid*16+16) of each row;
    // LDS dest is linear (wave base + lane*16), matching the HW semantics.
#pragma unroll
    for (int r = 0; r < NROW; ++r) {
        const int t = t0 - 3 + r;
        float* ldst = rows + r * ROW_F + d0;
        if (t >= 0) {   // block-uniform branch
            const float* gsrc = xb + (size_t)t * D_DIM + d0;
            __builtin_amdgcn_global_load_lds((const AS1 void*)gsrc,
                                             (AS3 void*)ldst, 16, 0, 0);
        } else {
            *(float4*)ldst = make_float4(0.f, 0.f, 0.f, 0.f);
        }
    }

    // small L2/L3-resident parameter loads overlap the DMA drain
    const float4 gv = *(const float4*)(g + d0);
    float wgt[4][4];
#pragma unroll
    for (int j = 0; j < 4; ++j) {
        float4 wv = *(const float4*)(w + (size_t)(d0 + j) * 4);
        wgt[j][0] = wv.x; wgt[j][1] = wv.y; wgt[j][2] = wv.z; wgt[j][3] = wv.w;
    }

    __syncthreads();   // compiler drains vmcnt+lgkmcnt here

    // ---- wave-per-row reduction: wave w sums row w from LDS ----
    if (wid < NROW) {
        const float* rp = rows + wid * ROW_F;
        float p = 0.f;
#pragma unroll
        for (int j = 0; j < 8; ++j) {
            // interleaved mapping: lane reads (j*64+lane)-th float4 of the
            // row; consecutive lanes -> adjacent 16B -> conflict-free.
            float4 v = *(const float4*)(rp + (j * 64 + lane) * 4);
            p = fmaf(v.x, v.x, p); p = fmaf(v.y, v.y, p);
            p = fmaf(v.z, v.z, p); p = fmaf(v.w, v.w, p);
        }
#pragma unroll
        for (int off = 32; off > 0; off >>= 1) p += __shfl_down(p, off, 64);
        if (lane == 0)
            inv_s[wid] = rsqrtf(p * (1.0f / D_DIM) + 1e-5f);
    }
    __syncthreads();

    // ---- normalize + conv + SiLU + store (no further barriers) ----
    float inv[NROW];
#pragma unroll
    for (int r = 0; r < NROW; ++r) inv[r] = inv_s[r];   // broadcast LDS reads

    float n[NROW][4];
#pragma unroll
    for (int r = 0; r < NROW; ++r) {
        float4 v = *(const float4*)(rows + r * ROW_F + d0);  // conflict-free
        n[r][0] = v.x * inv[r] * gv.x;
        n[r][1] = v.y * inv[r] * gv.y;
        n[r][2] = v.z * inv[r] * gv.z;
        n[r][3] = v.w * inv[r] * gv.w;
    }

    float* ob = out + (size_t)b * T_DIM * D_DIM + d0;
#pragma unroll
    for (int i = 0; i < TT; ++i) {
        float o[4];
#pragma unroll
        for (int j = 0; j < 4; ++j) {
            const float v = wgt[j][0] * n[i][j]     + wgt[j][1] * n[i + 1][j] +
                            wgt[j][2] * n[i + 2][j] + wgt[j][3] * n[i + 3][j];
            o[j] = silu(v);
        }
        nt_store4(ob + (size_t)(t0 + i) * D_DIM, o[0], o[1], o[2], o[3]);
    }
}

extern "C" void kernel_launch(void* const* d_in, const int* in_sizes, int n_in,
                              void* d_out, int out_size, void* d_ws, size_t ws_size,
                              hipStream_t stream) {
    const float* x = (const float*)d_in[0];
    const float* g = (const float*)d_in[1];   // norm_weight [D]
    const float* w = (const float*)d_in[2];   // conv_weight [D,1,K]
    float* out = (float*)d_out;

    const int total = in_sizes[0];            // B*T*D
    const int rows  = total / D_DIM;          // B*T
    const int B     = rows / T_DIM;

    dim3 grid(T_DIM / TT, B);
    fused_kernel<<<grid, NT, 0, stream>>>(x, g, w, out);
}